// Round 15
// baseline (872.451 us; speedup 1.0000x reference)
//
#include <hip/hip_runtime.h>
#include <hip/hip_bf16.h>
#include <math.h>

#define B_   16
#define S_   4096
#define DIN  1024
#define V_   512
#define FOUT 120

typedef __attribute__((ext_vector_type(8))) short bf16x8;
typedef __attribute__((ext_vector_type(4))) float f32x4;

#define AS1 __attribute__((address_space(1)))
#define AS3 __attribute__((address_space(3)))

__device__ const float CSCALE = 0.1f / (64.0f * 4096.0f);
__device__ const float EPSF = 1e-5f;

__device__ inline void gl2lds16(const void* g, void* l) {
  __builtin_amdgcn_global_load_lds((const AS1 unsigned int*)g,
                                   (AS3 unsigned int*)l, 16, 0, 0);
}

// fp32 -> bf16 RNE
__device__ inline unsigned short f2b(float f) {
  unsigned u = __builtin_bit_cast(unsigned, f);
  unsigned r = (u + 0x7FFFu + ((u >> 16) & 1u)) >> 16;
  return (unsigned short)r;
}

__device__ inline bf16x8 pack8(float4 a, float4 b) {
  bf16x8 r;
  r[0] = (short)f2b(a.x); r[1] = (short)f2b(a.y);
  r[2] = (short)f2b(a.z); r[3] = (short)f2b(a.w);
  r[4] = (short)f2b(b.x); r[5] = (short)f2b(b.y);
  r[6] = (short)f2b(b.z); r[7] = (short)f2b(b.w);
  return r;
}

// Wt frag-major (r7-r14-verified): chunk e = ((ct*32 + k)*24 + f)*64 + l ; f = 3*nf + g
// lane l: channel ct*128 + nf*16 + (l&15), k-elem k*32 + (l>>4)*8
__global__ void msr_convw(const float* __restrict__ Wq, const float* __restrict__ Wk,
                          const float* __restrict__ Wv, unsigned short* __restrict__ Wt) {
  int e = blockIdx.x * 256 + threadIdx.x;
  int l = e & 63;
  int f = (e >> 6) % 24;
  int ck = (e >> 6) / 24;
  int k = ck & 31;
  int ct = ck >> 5;
  int nf = f / 3, g = f % 3;
  const float* W = (g == 0) ? Wq : (g == 1) ? Wk : Wv;
  int ch = ct * 128 + nf * 16 + (l & 15);
  const float* src = W + (size_t)ch * DIN + k * 32 + (l >> 4) * 8;
  float4 a = *(const float4*)src;
  float4 b = *(const float4*)(src + 4);
  *(bf16x8*)(Wt + (size_t)e * 8) = pack8(a, b);
}

#define WAITVM7  asm volatile("s_waitcnt vmcnt(7)" ::: "memory")
#define WAITVM0  asm volatile("s_waitcnt vmcnt(0)" ::: "memory")
#define WAITLGKM asm volatile("s_waitcnt lgkmcnt(0)" ::: "memory")
#define SCHEDB   __builtin_amdgcn_sched_barrier(0)
#define BARRIER  { asm volatile("" ::: "memory"); __builtin_amdgcn_s_barrier(); asm volatile("" ::: "memory"); }

// Main (r12 skeleton; A-conversion fused): BM=256 x 128ch x 3g, BK=32, 32 steps,
// 512 thr = 8 waves (2M x 4N). Wave tile 128r x 32ch x 3g: acc[3][8][2]=192 AGPR.
// 3-buf LDS (3 x 40KB = A 16KB | B 24KB), 1 barrier/step.
// B: 3 gl2lds/wave-step (frag-major Wt, linear dest) staged k+2 ahead.
// A: x f32 loads issued k+2 ahead -> carried 1 step in regs -> pack8 ->
//    2 lane-linear ds_write_b128 for step k+1 (T14; latency fully hidden).
// Waits: pack's data-dep wait + explicit vmcnt(7) retire B(k+1) under any
// issue order (in-order vmcnt retirement); lgkmcnt(0) drains ds_writes.
__global__ __launch_bounds__(512, 2) void msr_main(
    const float* __restrict__ x, const unsigned short* __restrict__ Wt,
    float* __restrict__ outacc) {
  const int bid = blockIdx.x;
  const int xcd = bid & 7;
  const int j = bid >> 3;               // 0..127 per-XCD order
  const int ct = j & 3;                 // ct fastest: same rt 4x consecutive (L2-hot x)
  const int rt = xcd * 32 + (j >> 2);   // 0..255, bijective (r12-verified)
  const int r0 = rt << 8;

  __shared__ __align__(16) unsigned char smem_[122880];  // 3 x (A 16KB | B 24KB)

  const int t = threadIdx.x;
  const int w = t >> 6, lane = t & 63;
  const int l16 = lane * 16;
  const int w3 = w * 3;
  const int ctk = ct * 32;
  const int amb = (w >> 2) * 8192;                      // A m-frag base (bytes)
  const int bread = 16384 + 6 * (w & 3) * 1024 + l16;   // B frag read base (bytes)
  const int aw0 = (w * 64 + lane) * 16;                 // A write slot, chunk w
  const int aw1 = ((8 + w) * 64 + lane) * 16;           // A write slot, chunk 8+w

  // x source (r12-verified lane map): lane l -> row r0 + w*16 + (l&15),
  // k-octet l>>4 ; second chunk rows +128.
  const float* pXf = x + (size_t)(r0 + w * 16 + (lane & 15)) * DIN + ((lane >> 4) << 3);

  f32x4 acc[3][8][2];
#pragma unroll
  for (int g = 0; g < 3; ++g)
#pragma unroll
    for (int m = 0; m < 8; ++m)
#pragma unroll
      for (int n = 0; n < 2; ++n) acc[g][m][n] = (f32x4){0.f, 0.f, 0.f, 0.f};

  float4 xE[4], xO[4];   // x(k) carried one step: [0,1]=row chunk w, [2,3]=chunk 8+w

#define STAGEB(KK, SB) { \
  unsigned char* _sb = smem_ + (SB) * 40960; \
  _Pragma("unroll") for (int i = 0; i < 3; ++i) \
    gl2lds16(Wt + ((size_t)(ctk + (KK)) * 24 + w3 + i) * 512 + (size_t)lane * 8, \
             _sb + 16384 + (w3 + i) * 1024); }

#define LOADX(NX, KK) { \
  const float* _p0 = pXf + (size_t)(KK) * 32; \
  const float* _p1 = _p0 + (size_t)128 * DIN; \
  NX[0] = *(const float4*)_p0; NX[1] = *(const float4*)(_p0 + 4); \
  NX[2] = *(const float4*)_p1; NX[3] = *(const float4*)(_p1 + 4); }

#define WRITEA(CX, AB) { \
  unsigned char* _ab = smem_ + (AB) * 40960; \
  *(bf16x8*)(_ab + aw0) = pack8(CX[0], CX[1]); \
  *(bf16x8*)(_ab + aw1) = pack8(CX[2], CX[3]); }

#define COMPUTE(KB) { \
  const unsigned char* _kb = smem_ + (KB) * 40960; \
  bf16x8 _bfr[6]; \
  _Pragma("unroll") for (int i = 0; i < 6; ++i) \
    _bfr[i] = *(const bf16x8*)(_kb + bread + i * 1024); \
  __builtin_amdgcn_s_setprio(1); \
  _Pragma("unroll") for (int m = 0; m < 8; ++m) { \
    bf16x8 _afr = *(const bf16x8*)(_kb + amb + m * 1024 + l16); \
    _Pragma("unroll") for (int g = 0; g < 3; ++g) { \
      acc[g][m][0] = __builtin_amdgcn_mfma_f32_16x16x32_bf16(_afr, _bfr[g],     acc[g][m][0], 0, 0, 0); \
      acc[g][m][1] = __builtin_amdgcn_mfma_f32_16x16x32_bf16(_afr, _bfr[3 + g], acc[g][m][1], 0, 0, 0); \
    } \
  } \
  __builtin_amdgcn_s_setprio(0); }

// step KK (buf KB=KK%3): stage B(KK+2)->SB; issue x(KK+2)->NX; write A(KK+1)
// from CX into buf (KK+1)%3=AB; compute; vmcnt(7)+lgkm; barrier.
#define STEP(KB, SB, AB, KK, CX, NX) { \
  STAGEB((KK) + 2, SB); \
  LOADX(NX, (KK) + 2); \
  WRITEA(CX, AB); \
  SCHEDB; \
  COMPUTE(KB); \
  WAITVM7; WAITLGKM; \
  BARRIER; }

  // ---- prologue: x(0)->xE; B(0),B(1) staged; A(0) written; x(1)->xO ----
  LOADX(xE, 0);
  STAGEB(0, 0);
  STAGEB(1, 1);
  WRITEA(xE, 0);          // pack waits x(0); retires in-order
  LOADX(xO, 1);
  WAITVM7;                // retires B(0) (leaves B(1)x3 + x(1)x4 = 7)
  WAITLGKM;
  BARRIER;

  // ---- steps 0..29: 5 iters x 6 steps (buf period 3 x reg parity 2) ----
#pragma unroll 1
  for (int i = 0; i < 5; ++i) {
    const int k6 = i * 6;
    STEP(0, 2, 1, k6,     xO, xE);
    STEP(1, 0, 2, k6 + 1, xE, xO);
    STEP(2, 1, 0, k6 + 2, xO, xE);
    STEP(0, 2, 1, k6 + 3, xE, xO);
    STEP(1, 0, 2, k6 + 4, xO, xE);
    STEP(2, 1, 0, k6 + 5, xE, xO);
  }
  // ---- step 30 (buf 0): no stage; write A(31) from xO; full drain ----
  WRITEA(xO, 1);          // pack waits x(31) -> drains B(31) in-order
  SCHEDB;
  COMPUTE(0);
  WAITVM0; WAITLGKM;
  BARRIER;
  // ---- step 31 (buf 1): compute only ----
  COMPUTE(1);
#undef STEP
#undef COMPUTE
#undef WRITEA
#undef LOADX
#undef STAGEB

  // ---- epilogue (r12-verified): p = (q*k)[c^1]*v[c]; fold rows; atomicAdd ----
  float pd0 = 0.f, pd1 = 0.f;
#pragma unroll
  for (int m = 0; m < 8; ++m)
#pragma unroll
    for (int r = 0; r < 4; ++r) {
      float qk0 = acc[0][m][0][r] * acc[1][m][0][r];
      float qk1 = acc[0][m][1][r] * acc[1][m][1][r];
      pd0 += __shfl_xor(qk0, 1, 64) * acc[2][m][0][r];
      pd1 += __shfl_xor(qk1, 1, 64) * acc[2][m][1][r];
    }
  pd0 += __shfl_xor(pd0, 16, 64); pd0 += __shfl_xor(pd0, 32, 64);
  pd1 += __shfl_xor(pd1, 16, 64); pd1 += __shfl_xor(pd1, 32, 64);

  // rows r0..r0+255 in h-block rt>>1 ; d = ((w&3)*32 + n*16 + (lane&15)) % 64
  if (lane < 16) {
    float* dst = &outacc[((rt >> 1) << 6) + (w & 1) * 32 + lane];
    atomicAdd(dst, pd0);
    atomicAdd(dst + 16, pd1);
  }
}

// Finish: per-batch RMSNorm -> exact gelu -> @ Wout.T (verified r1-r14)
__global__ __launch_bounds__(256) void msr_finish(
    const float* __restrict__ outacc, const float* __restrict__ gamma,
    const float* __restrict__ Wout, float* __restrict__ y) {
  const int b = blockIdx.x;
  const int t = threadIdx.x;
  __shared__ float g[V_];
  __shared__ float wsum[4];

  float v0 = outacc[b * V_ + t] * CSCALE;
  float v1 = outacc[b * V_ + 256 + t] * CSCALE;
  float ss = v0 * v0 + v1 * v1;
#pragma unroll
  for (int o = 32; o > 0; o >>= 1) ss += __shfl_down(ss, o, 64);
  if ((t & 63) == 0) wsum[t >> 6] = ss;
  __syncthreads();
  float tot = wsum[0] + wsum[1] + wsum[2] + wsum[3];
  float rs = rsqrtf(tot * (1.0f / (float)V_) + EPSF);

  float r0v = v0 * rs * gamma[t];
  float r1v = v1 * rs * gamma[t + 256];
  g[t]       = 0.5f * r0v * (1.0f + erff(r0v * 0.70710678118654752f));
  g[t + 256] = 0.5f * r1v * (1.0f + erff(r1v * 0.70710678118654752f));
  __syncthreads();

  if (t < FOUT) {
    const float* wr = Wout + (size_t)t * V_;
    float acc = 0.f;
#pragma unroll 4
    for (int c = 0; c < V_; c += 4) {
      float4 w4 = *(const float4*)(wr + c);
      acc += g[c] * w4.x + g[c + 1] * w4.y + g[c + 2] * w4.z + g[c + 3] * w4.w;
    }
    y[b * FOUT + t] = acc;
  }
}

extern "C" void kernel_launch(void* const* d_in, const int* in_sizes, int n_in,
                              void* d_out, int out_size, void* d_ws, size_t ws_size,
                              hipStream_t stream) {
  const float* x     = (const float*)d_in[0];
  const float* Wq    = (const float*)d_in[1];
  const float* Wk    = (const float*)d_in[2];
  const float* Wv    = (const float*)d_in[3];
  const float* Wout  = (const float*)d_in[4];
  const float* gamma = (const float*)d_in[5];

  float* outacc = (float*)d_ws;                                  // 32 KB
  unsigned short* Wt = (unsigned short*)((char*)d_ws + 32768);   // 3 MB bf16 weights
  float* y = (float*)d_out;

  msr_convw<<<768, 256, 0, stream>>>(Wq, Wk, Wv, Wt);
  hipMemsetAsync(outacc, 0, B_ * V_ * sizeof(float), stream);
  msr_main<<<1024, 512, 0, stream>>>(x, Wt, outacc);
  msr_finish<<<B_, 256, 0, stream>>>(outacc, gamma, Wout, y);
}

// Round 16
// 289.164 us; speedup vs baseline: 3.0171x; 3.0171x over previous
//
#include <hip/hip_runtime.h>
#include <hip/hip_bf16.h>
#include <math.h>

#define B_   16
#define S_   4096
#define DIN  1024
#define V_   512
#define FOUT 120

typedef __attribute__((ext_vector_type(8))) short bf16x8;
typedef __attribute__((ext_vector_type(4))) float f32x4;

#define AS1 __attribute__((address_space(1)))
#define AS3 __attribute__((address_space(3)))

__device__ const float CSCALE = 0.1f / (64.0f * 4096.0f);
__device__ const float EPSF = 1e-5f;

__device__ inline void gl2lds16(const void* g, void* l) {
  __builtin_amdgcn_global_load_lds((const AS1 unsigned int*)g,
                                   (AS3 unsigned int*)l, 16, 0, 0);
}

// fp32 -> bf16 RNE
__device__ inline unsigned short f2b(float f) {
  unsigned u = __builtin_bit_cast(unsigned, f);
  unsigned r = (u + 0x7FFFu + ((u >> 16) & 1u)) >> 16;
  return (unsigned short)r;
}

__device__ inline bf16x8 pack8(float4 a, float4 b) {
  bf16x8 r;
  r[0] = (short)f2b(a.x); r[1] = (short)f2b(a.y);
  r[2] = (short)f2b(a.z); r[3] = (short)f2b(a.w);
  r[4] = (short)f2b(b.x); r[5] = (short)f2b(b.y);
  r[6] = (short)f2b(b.z); r[7] = (short)f2b(b.w);
  return r;
}

// Wt frag-major (r7-r15-verified): chunk e = ((ct128*32 + k)*24 + f)*64 + l ; f = 3*nf + g
// lane l: channel ct128*128 + nf*16 + (l&15), k-elem k*32 + (l>>4)*8
__global__ void msr_convw(const float* __restrict__ Wq, const float* __restrict__ Wk,
                          const float* __restrict__ Wv, unsigned short* __restrict__ Wt) {
  int e = blockIdx.x * 256 + threadIdx.x;
  int l = e & 63;
  int f = (e >> 6) % 24;
  int ck = (e >> 6) / 24;
  int k = ck & 31;
  int ct = ck >> 5;
  int nf = f / 3, g = f % 3;
  const float* W = (g == 0) ? Wq : (g == 1) ? Wk : Wv;
  int ch = ct * 128 + nf * 16 + (l & 15);
  const float* src = W + (size_t)ch * DIN + k * 32 + (l >> 4) * 8;
  float4 a = *(const float4*)src;
  float4 b = *(const float4*)(src + 4);
  *(bf16x8*)(Wt + (size_t)e * 8) = pack8(a, b);
}

// Xb = bf16(x), row-major [65536][1024] (r6-r12-verified)
__global__ __launch_bounds__(256) void msr_convx(const float* __restrict__ x,
                                                 unsigned short* __restrict__ Xb) {
  const size_t stride = (size_t)gridDim.x * 256;
  for (size_t i = blockIdx.x * 256ull + threadIdx.x; i < 8388608ull; i += stride) {
    const float* src = x + i * 8;
    float4 a = *(const float4*)src;
    float4 b = *(const float4*)(src + 4);
    *(bf16x8*)(Xb + i * 8) = pack8(a, b);
  }
}

#define WAITVM5  asm volatile("s_waitcnt vmcnt(5)" ::: "memory")
#define WAITVM3  asm volatile("s_waitcnt vmcnt(3)" ::: "memory")
#define WAITVM0  asm volatile("s_waitcnt vmcnt(0)" ::: "memory")
#define WAITLGKM asm volatile("s_waitcnt lgkmcnt(0)" ::: "memory")
#define SCHEDB   __builtin_amdgcn_sched_barrier(0)
#define BARRIER  { asm volatile("" ::: "memory"); __builtin_amdgcn_s_barrier(); asm volatile("" ::: "memory"); }

// Main: 256 thr = 4 waves (2M x 2N), block tile M=128 x 64ch x 3g, BK=32, 32 steps.
// Wave tile 64r x 32ch x 3g: acc[3][4][2] = 96 AGPR, ~150 unified regs/wave.
// 3-buf LDS (3 x 20KB = A 8KB | B 12KB) = 60KB -> TWO blocks/CU (two independent
// barrier domains; one block's MFMAs cover the other's ds_read/drain stalls).
// Sync skeleton = r12's proven 3-buf counted-vmcnt: stage k+2, one barrier/step,
// vmcnt(5) per step (5 gl2lds/wave-stage: 2 A + 3 B), vmcnt(0) only at tail.
template <bool DIRECT>
__global__ __launch_bounds__(256, 2) void msr_main(
    const float* __restrict__ x, const unsigned short* __restrict__ Xb,
    const unsigned short* __restrict__ Wt, float* __restrict__ outacc) {
  const int bid = blockIdx.x;
  const int xcd = bid & 7;
  const int j = bid >> 3;               // 0..511 per-XCD order
  const int ct = j & 7;                 // 8 ct-blocks of one rt consecutive (L2-hot x)
  const int rt = xcd * 64 + (j >> 3);   // 0..511, bijective
  const int r0 = rt << 7;

  __shared__ __align__(16) unsigned char smem_[61440];  // 3 x (A 8KB | B 12KB)

  const int t = threadIdx.x;
  const int w = t >> 6, lane = t & 63;
  const int l16 = lane * 16;
  const int w3 = w * 3;
  const int ct128 = ct >> 1;                          // 128-ch Wt image index
  const int fbase = (ct & 1) * 12 + w3;               // frag base within 24-frag image
  const int amb = (w >> 1) * 4096;                    // A m-half base (bytes)
  const int bread = 8192 + 6 * (w & 1) * 1024 + l16;  // B frag read base (bytes)

  // A staging (DIRECT, r12-verified map): wave w stages chunks {w, 4+w};
  // lane l -> row r0 + w*16 + (l&15), k-octet l>>4; linear LDS dest.
  const unsigned short* srcA0 =
      Xb + (size_t)(r0 + w * 16 + (lane & 15)) * DIN + ((lane >> 4) << 3);
  const unsigned short* srcA1 = srcA0 + (size_t)64 * DIN;
  // fallback: f32 + pack + lane-linear ds_write
  const float* pXf = x + (size_t)(r0 + w * 16 + (lane & 15)) * DIN + ((lane >> 4) << 3);

  f32x4 acc[3][4][2];
#pragma unroll
  for (int g = 0; g < 3; ++g)
#pragma unroll
    for (int m = 0; m < 4; ++m)
#pragma unroll
      for (int n = 0; n < 2; ++n) acc[g][m][n] = (f32x4){0.f, 0.f, 0.f, 0.f};

#define STAGE(KK, SB) { \
  unsigned char* _sb = smem_ + (SB) * 20480; \
  if constexpr (DIRECT) { \
    gl2lds16(srcA0 + (size_t)(KK) * 32, _sb + w * 1024); \
    gl2lds16(srcA1 + (size_t)(KK) * 32, _sb + (4 + w) * 1024); \
  } else { \
    const float* _p0 = pXf + (size_t)(KK) * 32; \
    const float* _p1 = _p0 + (size_t)64 * DIN; \
    *(bf16x8*)(_sb + (w * 64 + lane) * 16) = \
        pack8(*(const float4*)_p0, *(const float4*)(_p0 + 4)); \
    *(bf16x8*)(_sb + ((4 + w) * 64 + lane) * 16) = \
        pack8(*(const float4*)_p1, *(const float4*)(_p1 + 4)); \
  } \
  _Pragma("unroll") for (int i = 0; i < 3; ++i) \
    gl2lds16(Wt + ((size_t)(ct128 * 32 + (KK)) * 24 + fbase + i) * 512 + (size_t)lane * 8, \
             _sb + 8192 + (w3 + i) * 1024); }

#define COMPUTE(KB) { \
  const unsigned char* _kb = smem_ + (KB) * 20480; \
  bf16x8 _bfr[6]; \
  _Pragma("unroll") for (int i = 0; i < 6; ++i) \
    _bfr[i] = *(const bf16x8*)(_kb + bread + i * 1024); \
  __builtin_amdgcn_s_setprio(1); \
  _Pragma("unroll") for (int m = 0; m < 4; ++m) { \
    bf16x8 _afr = *(const bf16x8*)(_kb + amb + m * 1024 + l16); \
    _Pragma("unroll") for (int g = 0; g < 3; ++g) { \
      acc[g][m][0] = __builtin_amdgcn_mfma_f32_16x16x32_bf16(_afr, _bfr[g],     acc[g][m][0], 0, 0, 0); \
      acc[g][m][1] = __builtin_amdgcn_mfma_f32_16x16x32_bf16(_afr, _bfr[3 + g], acc[g][m][1], 0, 0, 0); \
    } \
  } \
  __builtin_amdgcn_s_setprio(0); }

#define STEP(KB, SB, KK, DOSTAGE, VMD, VMF) { \
  if (DOSTAGE) { STAGE((KK) + 2, SB); } \
  SCHEDB; \
  COMPUTE(KB); \
  if constexpr (DIRECT) { VMD; } else { WAITLGKM; VMF; } \
  BARRIER; }

  // ---- prologue: stage steps 0,1 into bufs 0,1 ----
  STAGE(0, 0);
  STAGE(1, 1);
  if constexpr (DIRECT) { WAITVM5; } else { WAITLGKM; WAITVM3; }
  BARRIER;

  // ---- steps 0..29 ----
#pragma unroll 1
  for (int i = 0; i < 10; ++i) {
    const int k3 = i * 3;
    STEP(0, 2, k3,     1, WAITVM5, WAITVM3);
    STEP(1, 0, k3 + 1, 1, WAITVM5, WAITVM3);
    STEP(2, 1, k3 + 2, 1, WAITVM5, WAITVM3);
  }
  // ---- step 30: no stage; full drain (incl. stage(31)) ----
  STEP(0, 0, 30, 0, WAITVM0, WAITVM0);
  // ---- step 31: compute only ----
  COMPUTE(1);
#undef STEP
#undef COMPUTE
#undef STAGE

  // ---- epilogue (r5-r15-verified): p = (q*k)[c^1]*v[c]; fold rows; atomicAdd ----
  float pd0 = 0.f, pd1 = 0.f;
#pragma unroll
  for (int m = 0; m < 4; ++m)
#pragma unroll
    for (int r = 0; r < 4; ++r) {
      float qk0 = acc[0][m][0][r] * acc[1][m][0][r];
      float qk1 = acc[0][m][1][r] * acc[1][m][1][r];
      pd0 += __shfl_xor(qk0, 1, 64) * acc[2][m][0][r];
      pd1 += __shfl_xor(qk1, 1, 64) * acc[2][m][1][r];
    }
  pd0 += __shfl_xor(pd0, 16, 64); pd0 += __shfl_xor(pd0, 32, 64);
  pd1 += __shfl_xor(pd1, 16, 64); pd1 += __shfl_xor(pd1, 32, 64);

  // rows r0..r0+127 in h-block rt>>2 ; d = (ct*64 + (w&1)*32 + n*16 + (lane&15)) % 64
  if (lane < 16) {
    float* dst = &outacc[((rt >> 2) << 6) + (w & 1) * 32 + lane];
    atomicAdd(dst, pd0);
    atomicAdd(dst + 16, pd1);
  }
}

// Finish: per-batch RMSNorm -> exact gelu -> @ Wout.T (verified r1-r15)
__global__ __launch_bounds__(256) void msr_finish(
    const float* __restrict__ outacc, const float* __restrict__ gamma,
    const float* __restrict__ Wout, float* __restrict__ y) {
  const int b = blockIdx.x;
  const int t = threadIdx.x;
  __shared__ float g[V_];
  __shared__ float wsum[4];

  float v0 = outacc[b * V_ + t] * CSCALE;
  float v1 = outacc[b * V_ + 256 + t] * CSCALE;
  float ss = v0 * v0 + v1 * v1;
#pragma unroll
  for (int o = 32; o > 0; o >>= 1) ss += __shfl_down(ss, o, 64);
  if ((t & 63) == 0) wsum[t >> 6] = ss;
  __syncthreads();
  float tot = wsum[0] + wsum[1] + wsum[2] + wsum[3];
  float rs = rsqrtf(tot * (1.0f / (float)V_) + EPSF);

  float r0v = v0 * rs * gamma[t];
  float r1v = v1 * rs * gamma[t + 256];
  g[t]       = 0.5f * r0v * (1.0f + erff(r0v * 0.70710678118654752f));
  g[t + 256] = 0.5f * r1v * (1.0f + erff(r1v * 0.70710678118654752f));
  __syncthreads();

  if (t < FOUT) {
    const float* wr = Wout + (size_t)t * V_;
    float acc = 0.f;
#pragma unroll 4
    for (int c = 0; c < V_; c += 4) {
      float4 w4 = *(const float4*)(wr + c);
      acc += g[c] * w4.x + g[c + 1] * w4.y + g[c + 2] * w4.z + g[c + 3] * w4.w;
    }
    y[b * FOUT + t] = acc;
  }
}

extern "C" void kernel_launch(void* const* d_in, const int* in_sizes, int n_in,
                              void* d_out, int out_size, void* d_ws, size_t ws_size,
                              hipStream_t stream) {
  const float* x     = (const float*)d_in[0];
  const float* Wq    = (const float*)d_in[1];
  const float* Wk    = (const float*)d_in[2];
  const float* Wv    = (const float*)d_in[3];
  const float* Wout  = (const float*)d_in[4];
  const float* gamma = (const float*)d_in[5];

  float* outacc = (float*)d_ws;                                    // 32 KB
  unsigned short* Wt = (unsigned short*)((char*)d_ws + 32768);     // 3 MB
  unsigned short* Xb = (unsigned short*)((char*)d_ws + 32768 + 3145728);  // 128 MB
  float* y = (float*)d_out;

  const size_t need = 32768ull + 3145728ull + 134217728ull;

  msr_convw<<<768, 256, 0, stream>>>(Wq, Wk, Wv, Wt);
  hipMemsetAsync(outacc, 0, B_ * V_ * sizeof(float), stream);

  if (ws_size >= need) {
    msr_convx<<<2048, 256, 0, stream>>>(x, Xb);
    msr_main<true><<<4096, 256, 0, stream>>>(x, Xb, Wt, outacc);
  } else {
    msr_main<false><<<4096, 256, 0, stream>>>(x, Xb, Wt, outacc);
  }
  msr_finish<<<B_, 256, 0, stream>>>(outacc, gamma, Wout, y);
}

// Round 17
// 245.122 us; speedup vs baseline: 3.5593x; 1.1797x over previous
//
#include <hip/hip_runtime.h>
#include <hip/hip_bf16.h>
#include <math.h>

#define B_   16
#define S_   4096
#define DIN  1024
#define V_   512
#define FOUT 120

typedef __attribute__((ext_vector_type(8))) short bf16x8;
typedef __attribute__((ext_vector_type(4))) float f32x4;

#define AS1 __attribute__((address_space(1)))
#define AS3 __attribute__((address_space(3)))

__device__ const float CSCALE = 0.1f / (64.0f * 4096.0f);
__device__ const float EPSF = 1e-5f;

__device__ inline void gl2lds16(const void* g, void* l) {
  __builtin_amdgcn_global_load_lds((const AS1 unsigned int*)g,
                                   (AS3 unsigned int*)l, 16, 0, 0);
}

// fp32 -> bf16 RNE
__device__ inline unsigned short f2b(float f) {
  unsigned u = __builtin_bit_cast(unsigned, f);
  unsigned r = (u + 0x7FFFu + ((u >> 16) & 1u)) >> 16;
  return (unsigned short)r;
}

__device__ inline bf16x8 pack8(float4 a, float4 b) {
  bf16x8 r;
  r[0] = (short)f2b(a.x); r[1] = (short)f2b(a.y);
  r[2] = (short)f2b(a.z); r[3] = (short)f2b(a.w);
  r[4] = (short)f2b(b.x); r[5] = (short)f2b(b.y);
  r[6] = (short)f2b(b.z); r[7] = (short)f2b(b.w);
  return r;
}

// Fused pre-pass: blocks 0..767 convert W (frag-major Wt, r7-r16-verified map);
// blocks 768..2815 convert x -> Xb bf16 (grid-stride, r6-r12-verified);
// last block zeroes outacc. Whole blocks per role -> no divergence.
template <bool DOX>
__global__ __launch_bounds__(256) void msr_conv(
    const float* __restrict__ Wq, const float* __restrict__ Wk,
    const float* __restrict__ Wv, const float* __restrict__ x,
    unsigned short* __restrict__ Wt, unsigned short* __restrict__ Xb,
    float* __restrict__ outacc) {
  const int bid = blockIdx.x;
  if (bid < 768) {
    // Wt frag-major: chunk e = ((ct*32 + k)*24 + f)*64 + l ; f = 3*nf + g
    // lane l: channel ct*128 + nf*16 + (l&15), k-elem k*32 + (l>>4)*8
    int e = bid * 256 + threadIdx.x;
    int l = e & 63;
    int f = (e >> 6) % 24;
    int ck = (e >> 6) / 24;
    int k = ck & 31;
    int ct = ck >> 5;
    int nf = f / 3, g = f % 3;
    const float* W = (g == 0) ? Wq : (g == 1) ? Wk : Wv;
    int ch = ct * 128 + nf * 16 + (l & 15);
    const float* src = W + (size_t)ch * DIN + k * 32 + (l >> 4) * 8;
    float4 a = *(const float4*)src;
    float4 b = *(const float4*)(src + 4);
    *(bf16x8*)(Wt + (size_t)e * 8) = pack8(a, b);
  } else if (DOX && bid < 2816) {
    const size_t stride = 2048ull * 256;
    for (size_t i = (size_t)(bid - 768) * 256 + threadIdx.x; i < 8388608ull; i += stride) {
      const float* src = x + i * 8;
      float4 a = *(const float4*)src;
      float4 b = *(const float4*)(src + 4);
      *(bf16x8*)(Xb + i * 8) = pack8(a, b);
    }
  } else {
    for (int i = threadIdx.x; i < B_ * V_; i += 256) outacc[i] = 0.f;
  }
}

#define WAITVM5  asm volatile("s_waitcnt vmcnt(5)" ::: "memory")
#define WAITVM3  asm volatile("s_waitcnt vmcnt(3)" ::: "memory")
#define WAITVM0  asm volatile("s_waitcnt vmcnt(0)" ::: "memory")
#define WAITLGKM asm volatile("s_waitcnt lgkmcnt(0)" ::: "memory")
#define SCHEDB   __builtin_amdgcn_sched_barrier(0)
#define BARRIER  { asm volatile("" ::: "memory"); __builtin_amdgcn_s_barrier(); asm volatile("" ::: "memory"); }

// Main — r12 VERBATIM (measured optimum: 174 us, MfmaUtil 52%, 0 conflicts):
// BM=256 x 128ch x 3g, BK=32, 32 steps, 512 thr = 8 waves (2M x 4N).
// Wave tile 128r x 32ch x 3g: acc[3][8][2] = 192 AGPR, bfr[6] held, afr streamed.
// 3-buf LDS pipeline (3 x 40KB), 1 barrier/step, counted vmcnt(5) (2 A + 3 B gl2lds).
template <bool DIRECT>
__global__ __launch_bounds__(512, 2) void msr_main(
    const float* __restrict__ x, const unsigned short* __restrict__ Xb,
    const unsigned short* __restrict__ Wt, float* __restrict__ outacc) {
  const int bid = blockIdx.x;
  const int xcd = bid & 7;
  const int j = bid >> 3;               // 0..127 per-XCD order
  const int ct = j & 3;                 // ct fastest: same rt 4x consecutive (L2-hot x)
  const int rt = xcd * 32 + (j >> 2);   // 0..255, bijective (r12-verified)
  const int r0 = rt << 8;

  __shared__ __align__(16) unsigned char smem_[122880];  // 3 x (A 16KB | B 24KB)

  const int t = threadIdx.x;
  const int w = t >> 6, lane = t & 63;
  const int l16 = lane * 16;
  const int w3 = w * 3;
  const int ctk = ct * 32;
  const int amb = (w >> 2) * 8192;                      // A m-frag base (bytes)
  const int bread = 16384 + 6 * (w & 3) * 1024 + l16;   // B frag read base (bytes)

  const unsigned short* srcA0 =
      Xb + (size_t)(r0 + w * 16 + (lane & 15)) * DIN + ((lane >> 4) << 3);
  const unsigned short* srcA1 = srcA0 + (size_t)128 * DIN;
  const float* pXf = x + (size_t)(r0 + w * 16 + (lane & 15)) * DIN + ((lane >> 4) << 3);

  f32x4 acc[3][8][2];
#pragma unroll
  for (int g = 0; g < 3; ++g)
#pragma unroll
    for (int m = 0; m < 8; ++m)
#pragma unroll
      for (int n = 0; n < 2; ++n) acc[g][m][n] = (f32x4){0.f, 0.f, 0.f, 0.f};

#define STAGE(KK, SB) { \
  unsigned char* _sb = smem_ + (SB) * 40960; \
  if constexpr (DIRECT) { \
    gl2lds16(srcA0 + (size_t)(KK) * 32, _sb + w * 1024); \
    gl2lds16(srcA1 + (size_t)(KK) * 32, _sb + (8 + w) * 1024); \
  } else { \
    const float* _p0 = pXf + (size_t)(KK) * 32; \
    const float* _p1 = _p0 + (size_t)128 * DIN; \
    *(bf16x8*)(_sb + (w * 64 + lane) * 16) = \
        pack8(*(const float4*)_p0, *(const float4*)(_p0 + 4)); \
    *(bf16x8*)(_sb + ((8 + w) * 64 + lane) * 16) = \
        pack8(*(const float4*)_p1, *(const float4*)(_p1 + 4)); \
  } \
  _Pragma("unroll") for (int i = 0; i < 3; ++i) \
    gl2lds16(Wt + ((size_t)(ctk + (KK)) * 24 + w3 + i) * 512 + (size_t)lane * 8, \
             _sb + 16384 + (w3 + i) * 1024); }

#define COMPUTE(KB) { \
  const unsigned char* _kb = smem_ + (KB) * 40960; \
  bf16x8 _bfr[6]; \
  _Pragma("unroll") for (int i = 0; i < 6; ++i) \
    _bfr[i] = *(const bf16x8*)(_kb + bread + i * 1024); \
  __builtin_amdgcn_s_setprio(1); \
  _Pragma("unroll") for (int m = 0; m < 8; ++m) { \
    bf16x8 _afr = *(const bf16x8*)(_kb + amb + m * 1024 + l16); \
    _Pragma("unroll") for (int g = 0; g < 3; ++g) { \
      acc[g][m][0] = __builtin_amdgcn_mfma_f32_16x16x32_bf16(_afr, _bfr[g],     acc[g][m][0], 0, 0, 0); \
      acc[g][m][1] = __builtin_amdgcn_mfma_f32_16x16x32_bf16(_afr, _bfr[3 + g], acc[g][m][1], 0, 0, 0); \
    } \
  } \
  __builtin_amdgcn_s_setprio(0); }

#define STEP(KB, SB, KK, DOSTAGE, VMD, VMF) { \
  if (DOSTAGE) { STAGE((KK) + 2, SB); } \
  SCHEDB; \
  COMPUTE(KB); \
  if constexpr (DIRECT) { VMD; } else { WAITLGKM; VMF; } \
  BARRIER; }

  // ---- prologue: stage steps 0,1 into bufs 0,1 ----
  STAGE(0, 0);
  STAGE(1, 1);
  if constexpr (DIRECT) { WAITVM5; } else { WAITLGKM; WAITVM3; }
  BARRIER;

  // ---- steps 0..29 ----
#pragma unroll 1
  for (int i = 0; i < 10; ++i) {
    const int k3 = i * 3;
    STEP(0, 2, k3,     1, WAITVM5, WAITVM3);
    STEP(1, 0, k3 + 1, 1, WAITVM5, WAITVM3);
    STEP(2, 1, k3 + 2, 1, WAITVM5, WAITVM3);
  }
  // ---- step 30: no stage; full drain (incl. stage(31)) ----
  STEP(0, 0, 30, 0, WAITVM0, WAITVM0);
  // ---- step 31: compute only ----
  COMPUTE(1);
#undef STEP
#undef COMPUTE
#undef STAGE

  // ---- epilogue (r12-verified): p = (q*k)[c^1]*v[c]; fold rows; atomicAdd ----
  float pd0 = 0.f, pd1 = 0.f;
#pragma unroll
  for (int m = 0; m < 8; ++m)
#pragma unroll
    for (int r = 0; r < 4; ++r) {
      float qk0 = acc[0][m][0][r] * acc[1][m][0][r];
      float qk1 = acc[0][m][1][r] * acc[1][m][1][r];
      pd0 += __shfl_xor(qk0, 1, 64) * acc[2][m][0][r];
      pd1 += __shfl_xor(qk1, 1, 64) * acc[2][m][1][r];
    }
  pd0 += __shfl_xor(pd0, 16, 64); pd0 += __shfl_xor(pd0, 32, 64);
  pd1 += __shfl_xor(pd1, 16, 64); pd1 += __shfl_xor(pd1, 32, 64);

  // rows r0..r0+255 in h-block rt>>1 ; d = ((w&3)*32 + n*16 + (lane&15)) % 64
  if (lane < 16) {
    float* dst = &outacc[((rt >> 1) << 6) + (w & 1) * 32 + lane];
    atomicAdd(dst, pd0);
    atomicAdd(dst + 16, pd1);
  }
}

// Finish: per-batch RMSNorm -> exact gelu -> @ Wout.T (verified r1-r16)
__global__ __launch_bounds__(256) void msr_finish(
    const float* __restrict__ outacc, const float* __restrict__ gamma,
    const float* __restrict__ Wout, float* __restrict__ y) {
  const int b = blockIdx.x;
  const int t = threadIdx.x;
  __shared__ float g[V_];
  __shared__ float wsum[4];

  float v0 = outacc[b * V_ + t] * CSCALE;
  float v1 = outacc[b * V_ + 256 + t] * CSCALE;
  float ss = v0 * v0 + v1 * v1;
#pragma unroll
  for (int o = 32; o > 0; o >>= 1) ss += __shfl_down(ss, o, 64);
  if ((t & 63) == 0) wsum[t >> 6] = ss;
  __syncthreads();
  float tot = wsum[0] + wsum[1] + wsum[2] + wsum[3];
  float rs = rsqrtf(tot * (1.0f / (float)V_) + EPSF);

  float r0v = v0 * rs * gamma[t];
  float r1v = v1 * rs * gamma[t + 256];
  g[t]       = 0.5f * r0v * (1.0f + erff(r0v * 0.70710678118654752f));
  g[t + 256] = 0.5f * r1v * (1.0f + erff(r1v * 0.70710678118654752f));
  __syncthreads();

  if (t < FOUT) {
    const float* wr = Wout + (size_t)t * V_;
    float acc = 0.f;
#pragma unroll 4
    for (int c = 0; c < V_; c += 4) {
      float4 w4 = *(const float4*)(wr + c);
      acc += g[c] * w4.x + g[c + 1] * w4.y + g[c + 2] * w4.z + g[c + 3] * w4.w;
    }
    y[b * FOUT + t] = acc;
  }
}

extern "C" void kernel_launch(void* const* d_in, const int* in_sizes, int n_in,
                              void* d_out, int out_size, void* d_ws, size_t ws_size,
                              hipStream_t stream) {
  const float* x     = (const float*)d_in[0];
  const float* Wq    = (const float*)d_in[1];
  const float* Wk    = (const float*)d_in[2];
  const float* Wv    = (const float*)d_in[3];
  const float* Wout  = (const float*)d_in[4];
  const float* gamma = (const float*)d_in[5];

  float* outacc = (float*)d_ws;                                    // 32 KB
  unsigned short* Wt = (unsigned short*)((char*)d_ws + 32768);     // 3 MB
  unsigned short* Xb = (unsigned short*)((char*)d_ws + 32768 + 3145728);  // 128 MB
  float* y = (float*)d_out;

  const size_t need = 32768ull + 3145728ull + 134217728ull;

  if (ws_size >= need) {
    msr_conv<true><<<2817, 256, 0, stream>>>(Wq, Wk, Wv, x, Wt, Xb, outacc);
    msr_main<true><<<1024, 512, 0, stream>>>(x, Xb, Wt, outacc);
  } else {
    msr_conv<false><<<769, 256, 0, stream>>>(Wq, Wk, Wv, x, Wt, Xb, outacc);
    msr_main<false><<<1024, 512, 0, stream>>>(x, Xb, Wt, outacc);
  }
  msr_finish<<<B_, 256, 0, stream>>>(outacc, gamma, Wout, y);
}